// Round 13
// baseline (93.650 us; speedup 1.0000x reference)
//
#include <hip/hip_runtime.h>
#include <stdint.h>

#define NE 256      // experts
#define TKG 4       // top-k groups
#define TK 8        // top-k experts
#define TPB 64      // tokens per block (256 threads = 4 waves; 16 tokens/wave)
#define CDW 76      // dwords per token row: 36 u64 slots (32 cand + 4 pad) + cnt + pad
#define CNT_OFF 72

typedef float pf2 __attribute__((ext_vector_type(2)));

// ---------- packed f32 VOP3P helpers (bit-identical IEEE, half the issues) ----------
__device__ __forceinline__ pf2 pk_fma_ss(pf2 a, pf2 b, pf2 cs) {
    pf2 d; asm("v_pk_fma_f32 %0, %1, %2, %3" : "=v"(d) : "v"(a), "v"(b), "s"(cs)); return d;
}
__device__ __forceinline__ pf2 pk_fma_sv(pf2 as, pf2 b, pf2 c) {
    pf2 d; asm("v_pk_fma_f32 %0, %1, %2, %3" : "=v"(d) : "s"(as), "v"(b), "v"(c)); return d;
}
__device__ __forceinline__ pf2 pk_fma_vv(pf2 a, pf2 b, pf2 c) {
    pf2 d; asm("v_pk_fma_f32 %0, %1, %2, %3" : "=v"(d) : "v"(a), "v"(b), "v"(c)); return d;
}
__device__ __forceinline__ pf2 pk_mul_s(pf2 a, pf2 bs) {
    pf2 d; asm("v_pk_mul_f32 %0, %1, %2" : "=v"(d) : "v"(a), "s"(bs)); return d;
}
__device__ __forceinline__ pf2 pk_mul_v(pf2 a, pf2 b) {
    pf2 d; asm("v_pk_mul_f32 %0, %1, %2" : "=v"(d) : "v"(a), "v"(b)); return d;
}
__device__ __forceinline__ pf2 pk_add_s(pf2 a, pf2 bs) {
    pf2 d; asm("v_pk_add_f32 %0, %1, %2" : "=v"(d) : "v"(a), "s"(bs)); return d;
}
__device__ __forceinline__ pf2 pk_add_v(pf2 a, pf2 b) {
    pf2 d; asm("v_pk_add_f32 %0, %1, %2" : "=v"(d) : "v"(a), "v"(b)); return d;
}

// Bit-exact packed replica of numpy's SIMD float32 exp (Cephes FMA path),
// magic-add RNE (validated r12). DO NOT TOUCH the value sequence.
__device__ __forceinline__ pf2 np_expf2(pf2 v, int* qi0, int* qi1) {
    const pf2 LOG2E  = {1.44269504088896341f, 1.44269504088896341f};
    const pf2 MAGIC  = {12582912.0f, 12582912.0f};     // 1.5 * 2^23
    const pf2 NMAGIC = {-12582912.0f, -12582912.0f};
    const pf2 NLN2HI = {-0.693359375f, -0.693359375f};
    const pf2 LN2LO  = {2.12194440e-4f, 2.12194440e-4f};
    const pf2 A0     = {1.9875691500E-4f, 1.9875691500E-4f};
    const pf2 A1     = {1.3981999507E-3f, 1.3981999507E-3f};
    const pf2 A2     = {8.3334519073E-3f, 8.3334519073E-3f};
    const pf2 A3     = {4.1665795894E-2f, 4.1665795894E-2f};
    const pf2 A4     = {1.6666665459E-1f, 1.6666665459E-1f};
    const pf2 A5     = {5.0000001201E-1f, 5.0000001201E-1f};
    const pf2 ONE    = {1.0f, 1.0f};

    pf2 m = pk_mul_s(v, LOG2E);
    pf2 y = pk_add_s(m, MAGIC);          // RNE-to-integer, biased (== rintf)
    pf2 qf = pk_add_s(y, NMAGIC);        // exact q as float (Sterbenz)
    *qi0 = __float_as_int(y.x) - 0x4B400000;   // exact integer q
    *qi1 = __float_as_int(y.y) - 0x4B400000;
    pf2 t = pk_fma_sv(NLN2HI, qf, v);
    t = pk_fma_sv(LN2LO, qf, t);
    pf2 t2 = pk_mul_v(t, t);
    pf2 p = pk_fma_sv(A0, t, A1);
    p = pk_fma_ss(p, t, A2);
    p = pk_fma_ss(p, t, A3);
    p = pk_fma_ss(p, t, A4);
    p = pk_fma_ss(p, t, A5);
    p = pk_fma_vv(p, t2, t);
    p = pk_add_s(p, ONE);
    return p;
}

// Packed correctly-rounded 1/d pair for d in [1, 2^20] (validated r10-r12).
__device__ __forceinline__ pf2 crdiv2(pf2 d) {
    const pf2 NEG1 = {-1.0f, -1.0f};
    const pf2 ONE  = {1.0f, 1.0f};
    pf2 nd = pk_mul_s(d, NEG1);          // exact sign flip
    pf2 y0;
    y0.x = __builtin_amdgcn_rcpf(d.x);
    y0.y = __builtin_amdgcn_rcpf(d.y);
    pf2 e0 = pk_fma_ss(nd, y0, ONE);
    pf2 y1 = pk_fma_vv(e0, y0, y0);
    pf2 e1 = pk_fma_ss(nd, y1, ONE);
    pf2 y2 = pk_fma_vv(e1, y1, y1);
    pf2 r  = pk_fma_ss(nd, y2, ONE);
    return pk_fma_vv(r, y2, y2);
}

// f32 -> monotone u32 (order-preserving). 0.0f -> 0x80000000.
__device__ __forceinline__ unsigned ordkey(float v) {
    int b = __float_as_int(v);
    return (unsigned)(b ^ ((b >> 31) | 0x80000000));
}
__device__ __forceinline__ float inv_ordkey(unsigned u) {
    unsigned b = (u & 0x80000000u) ? (u ^ 0x80000000u) : ~u;
    return __uint_as_float(b);
}

__device__ __forceinline__ float rlanef(float v, int l) {
    return __int_as_float(__builtin_amdgcn_readlane(__float_as_int(v), l));
}
__device__ __forceinline__ unsigned rlaneu(unsigned v, int l) {
    return (unsigned)__builtin_amdgcn_readlane((int)v, l);
}
__device__ __forceinline__ unsigned umax_(unsigned a, unsigned b) { return a > b ? a : b; }
__device__ __forceinline__ int mbcnt64(unsigned long long m) {
    return __builtin_amdgcn_mbcnt_hi((unsigned)(m >> 32),
           __builtin_amdgcn_mbcnt_lo((unsigned)m, 0u));
}

// DPP cross-lane read (pure VALU, no LDS).
template <int CTRL>
__device__ __forceinline__ float dppf(float x) {
    int xi = __float_as_int(x);
    return __int_as_float(__builtin_amdgcn_update_dpp(xi, xi, CTRL, 0xF, 0xF, false));
}
#define DPP_XOR1  0xB1   // quad_perm [1,0,3,2]
#define DPP_XOR2  0x4E   // quad_perm [2,3,0,1]
#define DPP_HMIRR 0x141  // row_half_mirror: l <-> l^7 within each 8
#define DPP_ROR8  0x128  // row_ror:8
#define DPP_BC15  0x142  // row_bcast15
#define DPP_BC31  0x143  // row_bcast31

// Branchless sorted-descending top-8 insertion (u64 = key<<32 | invidx).
// Zero candidates are exact no-ops (0 > v never holds with v init 0).
#define INS8(cand) do {                                                \
    const uint64_t c_ = (cand);                                        \
    const bool q0 = c_ > v0, q1 = c_ > v1, q2 = c_ > v2, q3 = c_ > v3; \
    const bool q4 = c_ > v4, q5 = c_ > v5, q6 = c_ > v6, q7 = c_ > v7; \
    v7 = q7 ? (q6 ? v6 : c_) : v7;                                     \
    v6 = q6 ? (q5 ? v5 : c_) : v6;                                     \
    v5 = q5 ? (q4 ? v4 : c_) : v5;                                     \
    v4 = q4 ? (q3 ? v3 : c_) : v4;                                     \
    v3 = q3 ? (q2 ? v2 : c_) : v3;                                     \
    v2 = q2 ? (q1 ? v1 : c_) : v2;                                     \
    v1 = q1 ? (q0 ? v0 : c_) : v1;                                     \
    v0 = q0 ? c_ : v0;                                                 \
} while (0)

// Full per-token phase-1. Value numerics bit-identical to r6-r12;
// candidate stores now UNCONDITIONAL (address-select to trash) — no exec churn.
__device__ __forceinline__ void score_token(
    const float4 cur, const pf2 biasL, const pf2 biasH,
    const int lane, const int bpa, uint32_t* row, uint32_t* trash)
{
    const pf2 ONE = {1.0f, 1.0f};
    int qa0, qa1, qb0, qb1;
    pf2 pA = np_expf2((pf2){-cur.x, -cur.y}, &qa0, &qa1);
    pf2 pB = np_expf2((pf2){-cur.z, -cur.w}, &qb0, &qb1);
    pf2 eA, eB;
    eA.x = ldexpf(pA.x, qa0);
    eA.y = ldexpf(pA.y, qa1);
    eB.x = ldexpf(pB.x, qb0);
    eB.y = ldexpf(pB.y, qb1);
    pf2 dA = pk_add_s(eA, ONE);
    pf2 dB = pk_add_s(eB, ONE);
    pf2 sA = crdiv2(dA);
    pf2 sB = crdiv2(dB);
    pf2 cA = pk_add_v(sA, biasL);
    pf2 cB = pk_add_v(sB, biasH);
    const float c0 = cA.x, c1 = cA.y, c2 = cB.x, c3 = cB.y;

    // local sorted top-2 of my 4 values
    float a1 = fmaxf(c0, c1), a2 = fminf(c0, c1);
    float d1 = fmaxf(c2, c3), d2 = fminf(c2, c3);
    float m1 = fmaxf(a1, d1);
    float m2 = fmaxf(fminf(a1, d1), fmaxf(a2, d2));

    // DPP butterfly within the 8-lane group (top-2 values tree-invariant)
    {
        float p1 = dppf<DPP_XOR1>(m1), p2 = dppf<DPP_XOR1>(m2);
        float n1 = fmaxf(m1, p1);
        m2 = fmaxf(fminf(m1, p1), fmaxf(m2, p2)); m1 = n1;
    }
    {
        float p1 = dppf<DPP_XOR2>(m1), p2 = dppf<DPP_XOR2>(m2);
        float n1 = fmaxf(m1, p1);
        m2 = fmaxf(fminf(m1, p1), fmaxf(m2, p2)); m1 = n1;
    }
    {
        float p1 = dppf<DPP_HMIRR>(m1), p2 = dppf<DPP_HMIRR>(m2);
        float n1 = fmaxf(m1, p1);
        m2 = fmaxf(fminf(m1, p1), fmaxf(m2, p2)); m1 = n1;
    }
    const float gs = m1 + m2;   // group-uniform

    // transpose-rank (one bpermute + 2 ballots + SALU byte popcounts)
    const float gb = __int_as_float(
        __builtin_amdgcn_ds_bpermute(bpa, __float_as_int(gs)));
    const unsigned long long gtm = __ballot(gb > gs);
    const unsigned long long eqm = __ballot(gb == gs);
    const unsigned long long term = gtm | (eqm & 0x7F3F1F0F07030100ull);
    unsigned km8 = 0;
    #pragma unroll
    for (int a = 0; a < 8; ++a)
        km8 |= (unsigned)(__popcll((term >> (8 * a)) & 0xFFull) < 4 ? 1u : 0u) << a;
    const int g = lane >> 3;
    const bool keep = (km8 >> g) & 1u;

    // tau0 = min over kept groups of m2 (DPP min-reduce; result at lane 63)
    const float inf_ = __uint_as_float(0x7F800000u);
    float mm = keep ? m2 : inf_;
    mm = fminf(mm, dppf<DPP_ROR8>(mm));
    mm = fminf(mm, dppf<DPP_BC15>(mm));
    mm = fminf(mm, dppf<DPP_BC31>(mm));
    const float t0f = rlanef(mm, 63);

    // candidate filter + ballot compaction
    const bool cd0 = keep && (c0 >= t0f);
    const bool cd1 = keep && (c1 >= t0f);
    const bool cd2 = keep && (c2 >= t0f);
    const bool cd3 = keep && (c3 >= t0f);
    const unsigned long long b0 = __ballot(cd0);
    const unsigned long long b1 = __ballot(cd1);
    const unsigned long long b2 = __ballot(cd2);
    const unsigned long long b3 = __ballot(cd3);
    const unsigned p1_ = __popcll(b0);
    const unsigned p2_ = p1_ + __popcll(b1);
    const unsigned p3_ = p2_ + __popcll(b2);
    unsigned cnt = p3_ + __popcll(b3);

    const unsigned k0 = ordkey(c0);
    const unsigned k1 = ordkey(c1);
    const unsigned k2 = ordkey(c2);
    const unsigned k3 = ordkey(c3);

    const int base = lane * 4;
    if (cnt <= 32u) {
        // unconditional stores: real slot if candidate, per-lane trash otherwise
        uint32_t* tr = &trash[lane * 2];
        uint32_t* w0 = cd0 ? &row[2 * (0u  + mbcnt64(b0))] : tr;
        uint32_t* w1 = cd1 ? &row[2 * (p1_ + mbcnt64(b1))] : tr;
        uint32_t* w2 = cd2 ? &row[2 * (p2_ + mbcnt64(b2))] : tr;
        uint32_t* w3 = cd3 ? &row[2 * (p3_ + mbcnt64(b3))] : tr;
        *reinterpret_cast<uint64_t*>(w0) = ((uint64_t)k0 << 32) | (unsigned)(255 - base);
        *reinterpret_cast<uint64_t*>(w1) = ((uint64_t)k1 << 32) | (unsigned)(255 - base - 1);
        *reinterpret_cast<uint64_t*>(w2) = ((uint64_t)k2 << 32) | (unsigned)(255 - base - 2);
        *reinterpret_cast<uint64_t*>(w3) = ((uint64_t)k3 << 32) | (unsigned)(255 - base - 3);
    } else {
        // exact fallback (unreachable in practice): 8 rounds of wave argmax
        unsigned mk0 = keep ? k0 : 0x80000000u;
        unsigned mk1 = keep ? k1 : 0x80000000u;
        unsigned mk2 = keep ? k2 : 0x80000000u;
        unsigned mk3 = keep ? k3 : 0x80000000u;
        for (int r = 0; r < TK; ++r) {
            unsigned h = umax_(umax_(mk0, mk1), umax_(mk2, mk3));
            unsigned m = h;
            m = umax_(m, (unsigned)__shfl_xor((int)m, 1));
            m = umax_(m, (unsigned)__shfl_xor((int)m, 2));
            m = umax_(m, (unsigned)__shfl_xor((int)m, 4));
            m = umax_(m, (unsigned)__shfl_xor((int)m, 8));
            const unsigned M = umax_(umax_(rlaneu(m, 0), rlaneu(m, 16)),
                                     umax_(rlaneu(m, 32), rlaneu(m, 48)));
            const unsigned long long bl = __ballot(h == M);
            const int wl = __ffsll(bl) - 1;
            const unsigned long long sb0 = __ballot(mk0 == M);
            const unsigned long long sb1 = __ballot(mk1 == M);
            const unsigned long long sb2 = __ballot(mk2 == M);
            const int slot = ((sb0 >> wl) & 1) ? 0 : ((sb1 >> wl) & 1) ? 1
                           : ((sb2 >> wl) & 1) ? 2 : 3;
            if (lane == r)
                *reinterpret_cast<uint64_t*>(&row[2 * r]) =
                    ((uint64_t)M << 32) | (unsigned)(255 - (wl * 4 + slot));
            const bool iw = (lane == wl);
            mk0 = (iw && slot == 0) ? 0u : mk0;
            mk1 = (iw && slot == 1) ? 0u : mk1;
            mk2 = (iw && slot == 2) ? 0u : mk2;
            mk3 = (iw && slot == 3) ? 0u : mk3;
        }
        cnt = 8;
    }
    // pad slots cnt..cnt+3 with zero keys (INS8 no-ops) for batched phase-2
    if (lane < 4)
        *reinterpret_cast<uint64_t*>(&row[2 * (cnt + lane)]) = 0ull;
    if (lane == 0) row[CNT_OFF] = cnt;
}

__global__ __launch_bounds__(256, 5) void route_kernel(
    const float* __restrict__ logits,
    const float* __restrict__ bias,
    float* __restrict__ out_idx_f,   // [T,8] indices stored as float
    float* __restrict__ out_w,       // [T,8] weights
    int T)
{
    __shared__ uint32_t cand[TPB * CDW];   // 19456 B (16B-aligned rows)
    __shared__ uint32_t trash[128];        // 512 B per-lane discard slots
    __shared__ float    bias_s[NE];        // 1024 B

    const int lane = threadIdx.x & 63;
    const int wvi  = threadIdx.x >> 6;
    const long long tok0 = (long long)blockIdx.x * TPB;

    bias_s[threadIdx.x] = bias[threadIdx.x];   // 256 threads == NE

    // ========== phase 1: wave-per-token scoring, 2-token ILP pairs ==========
    {
        const float4 bias4 = *reinterpret_cast<const float4*>(bias + lane * 4);
        const pf2 biasL = {bias4.x, bias4.y};
        const pf2 biasH = {bias4.z, bias4.w};
        const float* lp = logits + (tok0 + wvi * 16) * NE + lane * 4;
        uint32_t* wrow = &cand[(wvi * 16) * CDW];
        const int bpa = (lane & 7) << 5;   // bpermute byte-addr: lane (lane&7)*8

        float4 cA = *reinterpret_cast<const float4*>(lp);
        float4 cB = *reinterpret_cast<const float4*>(lp + NE);
        float4 nA, nB;
        for (int i = 0; i < 8; ++i) {
            if (i < 7) {
                nA = *reinterpret_cast<const float4*>(lp + (2 * i + 2) * NE);
                nB = *reinterpret_cast<const float4*>(lp + (2 * i + 3) * NE);
            }
            score_token(cA, biasL, biasH, lane, bpa, wrow + (2 * i) * CDW, trash);
            score_token(cB, biasL, biasH, lane, bpa, wrow + (2 * i + 1) * CDW, trash);
            cA = nA; cB = nB;
        }
    }
    __syncthreads();

    // ========== phase 2: thread-per-token batched top-8 + output ==========
    if (threadIdx.x < TPB) {
        uint32_t* row = &cand[threadIdx.x * CDW];
        const long long t = tok0 + threadIdx.x;
        const unsigned cnt = row[CNT_OFF];
        const unsigned iters = (cnt + 3) >> 2;

        uint64_t v0 = 0, v1 = 0, v2 = 0, v3 = 0, v4 = 0, v5 = 0, v6 = 0, v7 = 0;
        const ulonglong2* rp = reinterpret_cast<const ulonglong2*>(row);
        for (unsigned it = 0; it < iters; ++it) {
            const ulonglong2 a = rp[2 * it];       // ds_read_b128
            const ulonglong2 b = rp[2 * it + 1];   // ds_read_b128
            INS8(a.x); INS8(a.y); INS8(b.x); INS8(b.y);
        }

        const int e0 = 255 - (int)(v0 & 255u);
        const int e1 = 255 - (int)(v1 & 255u);
        const int e2 = 255 - (int)(v2 & 255u);
        const int e3 = 255 - (int)(v3 & 255u);
        const int e4 = 255 - (int)(v4 & 255u);
        const int e5 = 255 - (int)(v5 & 255u);
        const int e6 = 255 - (int)(v6 & 255u);
        const int e7 = 255 - (int)(v7 & 255u);
        const float s0 = inv_ordkey((unsigned)(v0 >> 32)) - bias_s[e0];
        const float s1 = inv_ordkey((unsigned)(v1 >> 32)) - bias_s[e1];
        const float s2 = inv_ordkey((unsigned)(v2 >> 32)) - bias_s[e2];
        const float s3 = inv_ordkey((unsigned)(v3 >> 32)) - bias_s[e3];
        const float s4 = inv_ordkey((unsigned)(v4 >> 32)) - bias_s[e4];
        const float s5 = inv_ordkey((unsigned)(v5 >> 32)) - bias_s[e5];
        const float s6 = inv_ordkey((unsigned)(v6 >> 32)) - bias_s[e6];
        const float s7 = inv_ordkey((unsigned)(v7 >> 32)) - bias_s[e7];

        const float denom = ((s0 + s1) + (s2 + s3)) + ((s4 + s5) + (s6 + s7));
        const float scale = 2.5f * __builtin_amdgcn_rcpf(denom + 1e-20f);

        float4* oi = reinterpret_cast<float4*>(out_idx_f + t * TK);
        float4* ow = reinterpret_cast<float4*>(out_w + t * TK);
        oi[0] = make_float4((float)e0, (float)e1, (float)e2, (float)e3);
        oi[1] = make_float4((float)e4, (float)e5, (float)e6, (float)e7);
        ow[0] = make_float4(s0 * scale, s1 * scale, s2 * scale, s3 * scale);
        ow[1] = make_float4(s4 * scale, s5 * scale, s6 * scale, s7 * scale);
    }
}

extern "C" void kernel_launch(void* const* d_in, const int* in_sizes, int n_in,
                              void* d_out, int out_size, void* d_ws, size_t ws_size,
                              hipStream_t stream) {
    const float* logits = (const float*)d_in[0];
    const float* bias   = (const float*)d_in[1];
    const int T = in_sizes[0] / NE;

    float* out_idx_f = (float*)d_out;
    float* out_w     = (float*)d_out + (size_t)T * TK;

    const int grid = T / TPB;   // 262144 / 64 = 4096
    route_kernel<<<grid, 256, 0, stream>>>(logits, bias, out_idx_f, out_w, T);
}

// Round 14
// 90.586 us; speedup vs baseline: 1.0338x; 1.0338x over previous
//
#include <hip/hip_runtime.h>
#include <stdint.h>

#define NE 256      // experts
#define TKG 4       // top-k groups
#define TK 8        // top-k experts
#define TPB 64      // tokens per block (256 threads = 4 waves; 16 tokens/wave)
#define CDW 76      // dwords per token row: 36 u64 slots (32 cand + 4 pad) + cnt; 304B, 16B-aligned
#define CNT_OFF 72

typedef float pf2 __attribute__((ext_vector_type(2)));

// ---------- packed f32 VOP3P helpers (bit-identical IEEE, half the issues) ----------
__device__ __forceinline__ pf2 pk_fma_ss(pf2 a, pf2 b, pf2 cs) {
    pf2 d; asm("v_pk_fma_f32 %0, %1, %2, %3" : "=v"(d) : "v"(a), "v"(b), "s"(cs)); return d;
}
__device__ __forceinline__ pf2 pk_fma_sv(pf2 as, pf2 b, pf2 c) {
    pf2 d; asm("v_pk_fma_f32 %0, %1, %2, %3" : "=v"(d) : "s"(as), "v"(b), "v"(c)); return d;
}
__device__ __forceinline__ pf2 pk_fma_vv(pf2 a, pf2 b, pf2 c) {
    pf2 d; asm("v_pk_fma_f32 %0, %1, %2, %3" : "=v"(d) : "v"(a), "v"(b), "v"(c)); return d;
}
__device__ __forceinline__ pf2 pk_mul_s(pf2 a, pf2 bs) {
    pf2 d; asm("v_pk_mul_f32 %0, %1, %2" : "=v"(d) : "v"(a), "s"(bs)); return d;
}
__device__ __forceinline__ pf2 pk_mul_v(pf2 a, pf2 b) {
    pf2 d; asm("v_pk_mul_f32 %0, %1, %2" : "=v"(d) : "v"(a), "v"(b)); return d;
}
__device__ __forceinline__ pf2 pk_add_s(pf2 a, pf2 bs) {
    pf2 d; asm("v_pk_add_f32 %0, %1, %2" : "=v"(d) : "v"(a), "s"(bs)); return d;
}

// Bit-exact packed replica of numpy's SIMD float32 exp (Cephes FMA path).
// DO NOT TOUCH — validated bit-exact vs the np reference (rounds 3-13).
__device__ __forceinline__ pf2 np_expf2(pf2 v) {
    const pf2 LOG2E  = {1.44269504088896341f, 1.44269504088896341f};
    const pf2 NLN2HI = {-0.693359375f, -0.693359375f};
    const pf2 LN2LO  = {2.12194440e-4f, 2.12194440e-4f};
    const pf2 A0     = {1.9875691500E-4f, 1.9875691500E-4f};
    const pf2 A1     = {1.3981999507E-3f, 1.3981999507E-3f};
    const pf2 A2     = {8.3334519073E-3f, 8.3334519073E-3f};
    const pf2 A3     = {4.1665795894E-2f, 4.1665795894E-2f};
    const pf2 A4     = {1.6666665459E-1f, 1.6666665459E-1f};
    const pf2 A5     = {5.0000001201E-1f, 5.0000001201E-1f};
    const pf2 ONE    = {1.0f, 1.0f};

    pf2 m = pk_mul_s(v, LOG2E);
    pf2 q; q.x = rintf(m.x); q.y = rintf(m.y);
    pf2 t = pk_fma_sv(NLN2HI, q, v);
    t = pk_fma_sv(LN2LO, q, t);
    pf2 t2 = pk_mul_v(t, t);
    pf2 p = pk_fma_sv(A0, t, A1);
    p = pk_fma_ss(p, t, A2);
    p = pk_fma_ss(p, t, A3);
    p = pk_fma_ss(p, t, A4);
    p = pk_fma_ss(p, t, A5);
    p = pk_fma_vv(p, t2, t);
    p = pk_add_s(p, ONE);
    pf2 r;
    r.x = ldexpf(p.x, (int)q.x);
    r.y = ldexpf(p.y, (int)q.y);
    return r;
}

// Correctly-rounded 1/d for d in [1, 2^20] (validated r10-r13).
__device__ __forceinline__ float crdiv1(float d) {
    float y0 = __builtin_amdgcn_rcpf(d);
    float e0 = fmaf(-d, y0, 1.0f);
    float y1 = fmaf(e0, y0, y0);
    float e1 = fmaf(-d, y1, 1.0f);
    float y2 = fmaf(e1, y1, y1);
    float r  = fmaf(-d, y2, 1.0f);
    return fmaf(r, y2, y2);
}

// f32 -> monotone u32 (order-preserving). 0.0f -> 0x80000000.
__device__ __forceinline__ unsigned ordkey(float v) {
    int b = __float_as_int(v);
    return (unsigned)(b ^ ((b >> 31) | 0x80000000));
}
__device__ __forceinline__ float inv_ordkey(unsigned u) {
    unsigned b = (u & 0x80000000u) ? (u ^ 0x80000000u) : ~u;
    return __uint_as_float(b);
}

__device__ __forceinline__ float rlanef(float v, int l) {
    return __int_as_float(__builtin_amdgcn_readlane(__float_as_int(v), l));
}
__device__ __forceinline__ unsigned rlaneu(unsigned v, int l) {
    return (unsigned)__builtin_amdgcn_readlane((int)v, l);
}
__device__ __forceinline__ unsigned umax_(unsigned a, unsigned b) { return a > b ? a : b; }
__device__ __forceinline__ int mbcnt64(unsigned long long m) {
    return __builtin_amdgcn_mbcnt_hi((unsigned)(m >> 32),
           __builtin_amdgcn_mbcnt_lo((unsigned)m, 0u));
}

// DPP cross-lane read (pure VALU, no LDS).
template <int CTRL>
__device__ __forceinline__ float dppf(float x) {
    int xi = __float_as_int(x);
    return __int_as_float(__builtin_amdgcn_update_dpp(xi, xi, CTRL, 0xF, 0xF, false));
}
#define DPP_XOR1  0xB1   // quad_perm [1,0,3,2]
#define DPP_XOR2  0x4E   // quad_perm [2,3,0,1]
#define DPP_HMIRR 0x141  // row_half_mirror: l <-> l^7 within each 8
#define DPP_ROR8  0x128  // row_ror:8
#define DPP_BC15  0x142  // row_bcast15
#define DPP_BC31  0x143  // row_bcast31

// Branchless sorted-descending top-8 insertion (u64 = key<<32 | invidx).
// Zero candidates are exact no-ops.
#define INS8(cand) do {                                                \
    const uint64_t c_ = (cand);                                        \
    const bool q0 = c_ > v0, q1 = c_ > v1, q2 = c_ > v2, q3 = c_ > v3; \
    const bool q4 = c_ > v4, q5 = c_ > v5, q6 = c_ > v6, q7 = c_ > v7; \
    v7 = q7 ? (q6 ? v6 : c_) : v7;                                     \
    v6 = q6 ? (q5 ? v5 : c_) : v6;                                     \
    v5 = q5 ? (q4 ? v4 : c_) : v5;                                     \
    v4 = q4 ? (q3 ? v3 : c_) : v4;                                     \
    v3 = q3 ? (q2 ? v2 : c_) : v3;                                     \
    v2 = q2 ? (q1 ? v1 : c_) : v2;                                     \
    v1 = q1 ? (q0 ? v0 : c_) : v1;                                     \
    v0 = q0 ? c_ : v0;                                                 \
} while (0)

// Full per-token phase-1 — byte-identical logic to the 89.7 µs r11 baseline,
// plus 4 zero-key pad slots after cnt (for the batched phase-2 b128 scan).
__device__ __forceinline__ void score_token(
    const float4 cur, const pf2 biasL, const pf2 biasH,
    const int lane, const int bpa, uint32_t* row)
{
    const pf2 ONE = {1.0f, 1.0f};
    pf2 eA = np_expf2((pf2){-cur.x, -cur.y});
    pf2 eB = np_expf2((pf2){-cur.z, -cur.w});
    pf2 dA = pk_add_s(eA, ONE);
    pf2 dB = pk_add_s(eB, ONE);
    const float s0 = crdiv1(dA.x);
    const float s1 = crdiv1(dA.y);
    const float s2 = crdiv1(dB.x);
    const float s3 = crdiv1(dB.y);
    const float c0 = s0 + biasL.x;
    const float c1 = s1 + biasL.y;
    const float c2 = s2 + biasH.x;
    const float c3 = s3 + biasH.y;

    // local sorted top-2 of my 4 values
    float a1 = fmaxf(c0, c1), a2 = fminf(c0, c1);
    float d1 = fmaxf(c2, c3), d2 = fminf(c2, c3);
    float m1 = fmaxf(a1, d1);
    float m2 = fmaxf(fminf(a1, d1), fmaxf(a2, d2));

    // DPP butterfly within the 8-lane group (top-2 values tree-invariant)
    {
        float p1 = dppf<DPP_XOR1>(m1), p2 = dppf<DPP_XOR1>(m2);
        float n1 = fmaxf(m1, p1);
        m2 = fmaxf(fminf(m1, p1), fmaxf(m2, p2)); m1 = n1;
    }
    {
        float p1 = dppf<DPP_XOR2>(m1), p2 = dppf<DPP_XOR2>(m2);
        float n1 = fmaxf(m1, p1);
        m2 = fmaxf(fminf(m1, p1), fmaxf(m2, p2)); m1 = n1;
    }
    {
        float p1 = dppf<DPP_HMIRR>(m1), p2 = dppf<DPP_HMIRR>(m2);
        float n1 = fmaxf(m1, p1);
        m2 = fmaxf(fminf(m1, p1), fmaxf(m2, p2)); m1 = n1;
    }
    const float gs = m1 + m2;   // group-uniform

    // transpose-rank (one bpermute + 2 ballots + SALU byte popcounts)
    const float gb = __int_as_float(
        __builtin_amdgcn_ds_bpermute(bpa, __float_as_int(gs)));
    const unsigned long long gtm = __ballot(gb > gs);
    const unsigned long long eqm = __ballot(gb == gs);
    const unsigned long long term = gtm | (eqm & 0x7F3F1F0F07030100ull);
    unsigned km8 = 0;
    #pragma unroll
    for (int a = 0; a < 8; ++a)
        km8 |= (unsigned)(__popcll((term >> (8 * a)) & 0xFFull) < 4 ? 1u : 0u) << a;
    const int g = lane >> 3;
    const bool keep = (km8 >> g) & 1u;

    // tau0 = min over kept groups of m2 (DPP min-reduce; result at lane 63)
    const float inf_ = __uint_as_float(0x7F800000u);
    float mm = keep ? m2 : inf_;
    mm = fminf(mm, dppf<DPP_ROR8>(mm));
    mm = fminf(mm, dppf<DPP_BC15>(mm));
    mm = fminf(mm, dppf<DPP_BC31>(mm));
    const float t0f = rlanef(mm, 63);

    // candidate filter + ballot compaction (exec-masked stores, as r11)
    const bool cd0 = keep && (c0 >= t0f);
    const bool cd1 = keep && (c1 >= t0f);
    const bool cd2 = keep && (c2 >= t0f);
    const bool cd3 = keep && (c3 >= t0f);
    const unsigned long long b0 = __ballot(cd0);
    const unsigned long long b1 = __ballot(cd1);
    const unsigned long long b2 = __ballot(cd2);
    const unsigned long long b3 = __ballot(cd3);
    const unsigned p1_ = __popcll(b0);
    const unsigned p2_ = p1_ + __popcll(b1);
    const unsigned p3_ = p2_ + __popcll(b2);
    unsigned cnt = p3_ + __popcll(b3);

    const unsigned k0 = ordkey(c0);
    const unsigned k1 = ordkey(c1);
    const unsigned k2 = ordkey(c2);
    const unsigned k3 = ordkey(c3);

    const int base = lane * 4;
    if (cnt <= 32u) {
        if (cd0) *reinterpret_cast<uint64_t*>(&row[2 * (0u  + mbcnt64(b0))]) =
            ((uint64_t)k0 << 32) | (unsigned)(255 - base);
        if (cd1) *reinterpret_cast<uint64_t*>(&row[2 * (p1_ + mbcnt64(b1))]) =
            ((uint64_t)k1 << 32) | (unsigned)(255 - base - 1);
        if (cd2) *reinterpret_cast<uint64_t*>(&row[2 * (p2_ + mbcnt64(b2))]) =
            ((uint64_t)k2 << 32) | (unsigned)(255 - base - 2);
        if (cd3) *reinterpret_cast<uint64_t*>(&row[2 * (p3_ + mbcnt64(b3))]) =
            ((uint64_t)k3 << 32) | (unsigned)(255 - base - 3);
    } else {
        // exact fallback (unreachable in practice): 8 rounds of wave argmax
        unsigned mk0 = keep ? k0 : 0x80000000u;
        unsigned mk1 = keep ? k1 : 0x80000000u;
        unsigned mk2 = keep ? k2 : 0x80000000u;
        unsigned mk3 = keep ? k3 : 0x80000000u;
        for (int r = 0; r < TK; ++r) {
            unsigned h = umax_(umax_(mk0, mk1), umax_(mk2, mk3));
            unsigned m = h;
            m = umax_(m, (unsigned)__shfl_xor((int)m, 1));
            m = umax_(m, (unsigned)__shfl_xor((int)m, 2));
            m = umax_(m, (unsigned)__shfl_xor((int)m, 4));
            m = umax_(m, (unsigned)__shfl_xor((int)m, 8));
            const unsigned M = umax_(umax_(rlaneu(m, 0), rlaneu(m, 16)),
                                     umax_(rlaneu(m, 32), rlaneu(m, 48)));
            const unsigned long long bl = __ballot(h == M);
            const int wl = __ffsll(bl) - 1;
            const unsigned long long sb0 = __ballot(mk0 == M);
            const unsigned long long sb1 = __ballot(mk1 == M);
            const unsigned long long sb2 = __ballot(mk2 == M);
            const int slot = ((sb0 >> wl) & 1) ? 0 : ((sb1 >> wl) & 1) ? 1
                           : ((sb2 >> wl) & 1) ? 2 : 3;
            if (lane == r)
                *reinterpret_cast<uint64_t*>(&row[2 * r]) =
                    ((uint64_t)M << 32) | (unsigned)(255 - (wl * 4 + slot));
            const bool iw = (lane == wl);
            mk0 = (iw && slot == 0) ? 0u : mk0;
            mk1 = (iw && slot == 1) ? 0u : mk1;
            mk2 = (iw && slot == 2) ? 0u : mk2;
            mk3 = (iw && slot == 3) ? 0u : mk3;
        }
        cnt = 8;
    }
    // pad slots cnt..cnt+3 with zero keys (INS8 no-ops) for batched phase-2
    if (lane < 4)
        *reinterpret_cast<uint64_t*>(&row[2 * (cnt + lane)]) = 0ull;
    if (lane == 0) row[CNT_OFF] = cnt;
}

__global__ __launch_bounds__(256, 4) void route_kernel(
    const float* __restrict__ logits,
    const float* __restrict__ bias,
    float* __restrict__ out_idx_f,   // [T,8] indices stored as float
    float* __restrict__ out_w,       // [T,8] weights
    int T)
{
    __shared__ uint32_t cand[TPB * CDW];   // 19456 B (16B-aligned rows)
    __shared__ float    bias_s[NE];        // 1024 B

    const int lane = threadIdx.x & 63;
    const int wvi  = threadIdx.x >> 6;
    const long long tok0 = (long long)blockIdx.x * TPB;

    bias_s[threadIdx.x] = bias[threadIdx.x];   // 256 threads == NE

    // ========== phase 1: wave-per-token scoring, 2-token ILP pairs ==========
    {
        const float4 bias4 = *reinterpret_cast<const float4*>(bias + lane * 4);
        const pf2 biasL = {bias4.x, bias4.y};
        const pf2 biasH = {bias4.z, bias4.w};
        const float* lp = logits + (tok0 + wvi * 16) * NE + lane * 4;
        uint32_t* wrow = &cand[(wvi * 16) * CDW];
        const int bpa = (lane & 7) << 5;   // bpermute byte-addr: lane (lane&7)*8

        float4 cA = *reinterpret_cast<const float4*>(lp);
        float4 cB = *reinterpret_cast<const float4*>(lp + NE);
        float4 nA, nB;
        for (int i = 0; i < 8; ++i) {
            if (i < 7) {
                nA = *reinterpret_cast<const float4*>(lp + (2 * i + 2) * NE);
                nB = *reinterpret_cast<const float4*>(lp + (2 * i + 3) * NE);
            }
            score_token(cA, biasL, biasH, lane, bpa, wrow + (2 * i) * CDW);
            score_token(cB, biasL, biasH, lane, bpa, wrow + (2 * i + 1) * CDW);
            cA = nA; cB = nB;
        }
    }
    __syncthreads();

    // ========== phase 2: thread-per-token batched top-8 + output ==========
    if (threadIdx.x < TPB) {
        uint32_t* row = &cand[threadIdx.x * CDW];
        const long long t = tok0 + threadIdx.x;
        const unsigned cnt = row[CNT_OFF];
        const unsigned iters = (cnt + 3) >> 2;

        uint64_t v0 = 0, v1 = 0, v2 = 0, v3 = 0, v4 = 0, v5 = 0, v6 = 0, v7 = 0;
        const ulonglong2* rp = reinterpret_cast<const ulonglong2*>(row);
        for (unsigned it = 0; it < iters; ++it) {
            const ulonglong2 a = rp[2 * it];       // ds_read_b128
            const ulonglong2 b = rp[2 * it + 1];   // ds_read_b128
            INS8(a.x); INS8(a.y); INS8(b.x); INS8(b.y);
        }

        const int e0 = 255 - (int)(v0 & 255u);
        const int e1 = 255 - (int)(v1 & 255u);
        const int e2 = 255 - (int)(v2 & 255u);
        const int e3 = 255 - (int)(v3 & 255u);
        const int e4 = 255 - (int)(v4 & 255u);
        const int e5 = 255 - (int)(v5 & 255u);
        const int e6 = 255 - (int)(v6 & 255u);
        const int e7 = 255 - (int)(v7 & 255u);
        const float s0 = inv_ordkey((unsigned)(v0 >> 32)) - bias_s[e0];
        const float s1 = inv_ordkey((unsigned)(v1 >> 32)) - bias_s[e1];
        const float s2 = inv_ordkey((unsigned)(v2 >> 32)) - bias_s[e2];
        const float s3 = inv_ordkey((unsigned)(v3 >> 32)) - bias_s[e3];
        const float s4 = inv_ordkey((unsigned)(v4 >> 32)) - bias_s[e4];
        const float s5 = inv_ordkey((unsigned)(v5 >> 32)) - bias_s[e5];
        const float s6 = inv_ordkey((unsigned)(v6 >> 32)) - bias_s[e6];
        const float s7 = inv_ordkey((unsigned)(v7 >> 32)) - bias_s[e7];

        const float denom = ((s0 + s1) + (s2 + s3)) + ((s4 + s5) + (s6 + s7));
        const float scale = 2.5f * __builtin_amdgcn_rcpf(denom + 1e-20f);

        float4* oi = reinterpret_cast<float4*>(out_idx_f + t * TK);
        float4* ow = reinterpret_cast<float4*>(out_w + t * TK);
        oi[0] = make_float4((float)e0, (float)e1, (float)e2, (float)e3);
        oi[1] = make_float4((float)e4, (float)e5, (float)e6, (float)e7);
        ow[0] = make_float4(s0 * scale, s1 * scale, s2 * scale, s3 * scale);
        ow[1] = make_float4(s4 * scale, s5 * scale, s6 * scale, s7 * scale);
    }
}

extern "C" void kernel_launch(void* const* d_in, const int* in_sizes, int n_in,
                              void* d_out, int out_size, void* d_ws, size_t ws_size,
                              hipStream_t stream) {
    const float* logits = (const float*)d_in[0];
    const float* bias   = (const float*)d_in[1];
    const int T = in_sizes[0] / NE;

    float* out_idx_f = (float*)d_out;
    float* out_w     = (float*)d_out + (size_t)T * TK;

    const int grid = T / TPB;   // 262144 / 64 = 4096
    route_kernel<<<grid, 256, 0, stream>>>(logits, bias, out_idx_f, out_w, T);
}

// Round 15
// 90.523 us; speedup vs baseline: 1.0346x; 1.0007x over previous
//
#include <hip/hip_runtime.h>
#include <stdint.h>

#define NE 256      // experts
#define TKG 4       // top-k groups
#define TK 8        // top-k experts
#define TPB 64      // tokens per block (256 threads = 4 waves; 16 tokens/wave)
#define CDW 76      // dwords per token row: 36 u64 slots (32 cand + 4 pad) + cnt; 304B, 16B-aligned
#define CNT_OFF 72

typedef float pf2 __attribute__((ext_vector_type(2)));

// ---------- packed f32 VOP3P helpers (bit-identical IEEE, half the issues) ----------
__device__ __forceinline__ pf2 pk_fma_ss(pf2 a, pf2 b, pf2 cs) {
    pf2 d; asm("v_pk_fma_f32 %0, %1, %2, %3" : "=v"(d) : "v"(a), "v"(b), "s"(cs)); return d;
}
__device__ __forceinline__ pf2 pk_fma_sv(pf2 as, pf2 b, pf2 c) {
    pf2 d; asm("v_pk_fma_f32 %0, %1, %2, %3" : "=v"(d) : "s"(as), "v"(b), "v"(c)); return d;
}
__device__ __forceinline__ pf2 pk_fma_vv(pf2 a, pf2 b, pf2 c) {
    pf2 d; asm("v_pk_fma_f32 %0, %1, %2, %3" : "=v"(d) : "v"(a), "v"(b), "v"(c)); return d;
}
__device__ __forceinline__ pf2 pk_mul_s(pf2 a, pf2 bs) {
    pf2 d; asm("v_pk_mul_f32 %0, %1, %2" : "=v"(d) : "v"(a), "s"(bs)); return d;
}
__device__ __forceinline__ pf2 pk_mul_v(pf2 a, pf2 b) {
    pf2 d; asm("v_pk_mul_f32 %0, %1, %2" : "=v"(d) : "v"(a), "v"(b)); return d;
}
__device__ __forceinline__ pf2 pk_add_s(pf2 a, pf2 bs) {
    pf2 d; asm("v_pk_add_f32 %0, %1, %2" : "=v"(d) : "v"(a), "s"(bs)); return d;
}

// Bit-exact packed replica of numpy's SIMD float32 exp (Cephes FMA path).
// DO NOT TOUCH — validated bit-exact vs the np reference (rounds 3-14).
__device__ __forceinline__ pf2 np_expf2(pf2 v) {
    const pf2 LOG2E  = {1.44269504088896341f, 1.44269504088896341f};
    const pf2 NLN2HI = {-0.693359375f, -0.693359375f};
    const pf2 LN2LO  = {2.12194440e-4f, 2.12194440e-4f};
    const pf2 A0     = {1.9875691500E-4f, 1.9875691500E-4f};
    const pf2 A1     = {1.3981999507E-3f, 1.3981999507E-3f};
    const pf2 A2     = {8.3334519073E-3f, 8.3334519073E-3f};
    const pf2 A3     = {4.1665795894E-2f, 4.1665795894E-2f};
    const pf2 A4     = {1.6666665459E-1f, 1.6666665459E-1f};
    const pf2 A5     = {5.0000001201E-1f, 5.0000001201E-1f};
    const pf2 ONE    = {1.0f, 1.0f};

    pf2 m = pk_mul_s(v, LOG2E);
    pf2 q; q.x = rintf(m.x); q.y = rintf(m.y);
    pf2 t = pk_fma_sv(NLN2HI, q, v);
    t = pk_fma_sv(LN2LO, q, t);
    pf2 t2 = pk_mul_v(t, t);
    pf2 p = pk_fma_sv(A0, t, A1);
    p = pk_fma_ss(p, t, A2);
    p = pk_fma_ss(p, t, A3);
    p = pk_fma_ss(p, t, A4);
    p = pk_fma_ss(p, t, A5);
    p = pk_fma_vv(p, t2, t);
    p = pk_add_s(p, ONE);
    pf2 r;
    r.x = ldexpf(p.x, (int)q.x);
    r.y = ldexpf(p.y, (int)q.y);
    return r;
}

// Correctly-rounded 1/d for d in [1, 2^20] (validated r10-r14).
__device__ __forceinline__ float crdiv1(float d) {
    float y0 = __builtin_amdgcn_rcpf(d);
    float e0 = fmaf(-d, y0, 1.0f);
    float y1 = fmaf(e0, y0, y0);
    float e1 = fmaf(-d, y1, 1.0f);
    float y2 = fmaf(e1, y1, y1);
    float r  = fmaf(-d, y2, 1.0f);
    return fmaf(r, y2, y2);
}

// f32 -> monotone u32 (order-preserving). 0.0f -> 0x80000000.
__device__ __forceinline__ unsigned ordkey(float v) {
    int b = __float_as_int(v);
    return (unsigned)(b ^ ((b >> 31) | 0x80000000));
}
__device__ __forceinline__ float inv_ordkey(unsigned u) {
    unsigned b = (u & 0x80000000u) ? (u ^ 0x80000000u) : ~u;
    return __uint_as_float(b);
}

__device__ __forceinline__ float rlanef(float v, int l) {
    return __int_as_float(__builtin_amdgcn_readlane(__float_as_int(v), l));
}
__device__ __forceinline__ unsigned rlaneu(unsigned v, int l) {
    return (unsigned)__builtin_amdgcn_readlane((int)v, l);
}
__device__ __forceinline__ unsigned umax_(unsigned a, unsigned b) { return a > b ? a : b; }
__device__ __forceinline__ int mbcnt64(unsigned long long m) {
    return __builtin_amdgcn_mbcnt_hi((unsigned)(m >> 32),
           __builtin_amdgcn_mbcnt_lo((unsigned)m, 0u));
}

// DPP cross-lane read (pure VALU, no LDS).
template <int CTRL>
__device__ __forceinline__ float dppf(float x) {
    int xi = __float_as_int(x);
    return __int_as_float(__builtin_amdgcn_update_dpp(xi, xi, CTRL, 0xF, 0xF, false));
}
#define DPP_XOR1  0xB1   // quad_perm [1,0,3,2]
#define DPP_XOR2  0x4E   // quad_perm [2,3,0,1]
#define DPP_HMIRR 0x141  // row_half_mirror: l <-> l^7 within each 8
#define DPP_ROR8  0x128  // row_ror:8
#define DPP_BC15  0x142  // row_bcast15
#define DPP_BC31  0x143  // row_bcast31

// Branchless sorted-descending top-8 insertion (u64 = key<<32 | invidx).
// Zero candidates are exact no-ops.
#define INS8(cand) do {                                                \
    const uint64_t c_ = (cand);                                        \
    const bool q0 = c_ > v0, q1 = c_ > v1, q2 = c_ > v2, q3 = c_ > v3; \
    const bool q4 = c_ > v4, q5 = c_ > v5, q6 = c_ > v6, q7 = c_ > v7; \
    v7 = q7 ? (q6 ? v6 : c_) : v7;                                     \
    v6 = q6 ? (q5 ? v5 : c_) : v6;                                     \
    v5 = q5 ? (q4 ? v4 : c_) : v5;                                     \
    v4 = q4 ? (q3 ? v3 : c_) : v4;                                     \
    v3 = q3 ? (q2 ? v2 : c_) : v3;                                     \
    v2 = q2 ? (q1 ? v1 : c_) : v2;                                     \
    v1 = q1 ? (q0 ? v0 : c_) : v1;                                     \
    v0 = q0 ? c_ : v0;                                                 \
} while (0)

// Full per-token phase-1 — byte-identical logic to r14.
__device__ __forceinline__ void score_token(
    const float4 cur, const pf2 biasL, const pf2 biasH,
    const int lane, const int bpa, uint32_t* row)
{
    const pf2 ONE = {1.0f, 1.0f};
    pf2 eA = np_expf2((pf2){-cur.x, -cur.y});
    pf2 eB = np_expf2((pf2){-cur.z, -cur.w});
    pf2 dA = pk_add_s(eA, ONE);
    pf2 dB = pk_add_s(eB, ONE);
    const float s0 = crdiv1(dA.x);
    const float s1 = crdiv1(dA.y);
    const float s2 = crdiv1(dB.x);
    const float s3 = crdiv1(dB.y);
    const float c0 = s0 + biasL.x;
    const float c1 = s1 + biasL.y;
    const float c2 = s2 + biasH.x;
    const float c3 = s3 + biasH.y;

    // local sorted top-2 of my 4 values
    float a1 = fmaxf(c0, c1), a2 = fminf(c0, c1);
    float d1 = fmaxf(c2, c3), d2 = fminf(c2, c3);
    float m1 = fmaxf(a1, d1);
    float m2 = fmaxf(fminf(a1, d1), fmaxf(a2, d2));

    // DPP butterfly within the 8-lane group (top-2 values tree-invariant)
    {
        float p1 = dppf<DPP_XOR1>(m1), p2 = dppf<DPP_XOR1>(m2);
        float n1 = fmaxf(m1, p1);
        m2 = fmaxf(fminf(m1, p1), fmaxf(m2, p2)); m1 = n1;
    }
    {
        float p1 = dppf<DPP_XOR2>(m1), p2 = dppf<DPP_XOR2>(m2);
        float n1 = fmaxf(m1, p1);
        m2 = fmaxf(fminf(m1, p1), fmaxf(m2, p2)); m1 = n1;
    }
    {
        float p1 = dppf<DPP_HMIRR>(m1), p2 = dppf<DPP_HMIRR>(m2);
        float n1 = fmaxf(m1, p1);
        m2 = fmaxf(fminf(m1, p1), fmaxf(m2, p2)); m1 = n1;
    }
    const float gs = m1 + m2;   // group-uniform

    // transpose-rank (one bpermute + 2 ballots + SALU byte popcounts)
    const float gb = __int_as_float(
        __builtin_amdgcn_ds_bpermute(bpa, __float_as_int(gs)));
    const unsigned long long gtm = __ballot(gb > gs);
    const unsigned long long eqm = __ballot(gb == gs);
    const unsigned long long term = gtm | (eqm & 0x7F3F1F0F07030100ull);
    unsigned km8 = 0;
    #pragma unroll
    for (int a = 0; a < 8; ++a)
        km8 |= (unsigned)(__popcll((term >> (8 * a)) & 0xFFull) < 4 ? 1u : 0u) << a;
    const int g = lane >> 3;
    const bool keep = (km8 >> g) & 1u;

    // tau0 = min over kept groups of m2 (DPP min-reduce; result at lane 63)
    const float inf_ = __uint_as_float(0x7F800000u);
    float mm = keep ? m2 : inf_;
    mm = fminf(mm, dppf<DPP_ROR8>(mm));
    mm = fminf(mm, dppf<DPP_BC15>(mm));
    mm = fminf(mm, dppf<DPP_BC31>(mm));
    const float t0f = rlanef(mm, 63);

    // candidate filter + ballot compaction (exec-masked stores, as r11/r14)
    const bool cd0 = keep && (c0 >= t0f);
    const bool cd1 = keep && (c1 >= t0f);
    const bool cd2 = keep && (c2 >= t0f);
    const bool cd3 = keep && (c3 >= t0f);
    const unsigned long long b0 = __ballot(cd0);
    const unsigned long long b1 = __ballot(cd1);
    const unsigned long long b2 = __ballot(cd2);
    const unsigned long long b3 = __ballot(cd3);
    const unsigned p1_ = __popcll(b0);
    const unsigned p2_ = p1_ + __popcll(b1);
    const unsigned p3_ = p2_ + __popcll(b2);
    unsigned cnt = p3_ + __popcll(b3);

    const unsigned k0 = ordkey(c0);
    const unsigned k1 = ordkey(c1);
    const unsigned k2 = ordkey(c2);
    const unsigned k3 = ordkey(c3);

    const int base = lane * 4;
    if (cnt <= 32u) {
        if (cd0) *reinterpret_cast<uint64_t*>(&row[2 * (0u  + mbcnt64(b0))]) =
            ((uint64_t)k0 << 32) | (unsigned)(255 - base);
        if (cd1) *reinterpret_cast<uint64_t*>(&row[2 * (p1_ + mbcnt64(b1))]) =
            ((uint64_t)k1 << 32) | (unsigned)(255 - base - 1);
        if (cd2) *reinterpret_cast<uint64_t*>(&row[2 * (p2_ + mbcnt64(b2))]) =
            ((uint64_t)k2 << 32) | (unsigned)(255 - base - 2);
        if (cd3) *reinterpret_cast<uint64_t*>(&row[2 * (p3_ + mbcnt64(b3))]) =
            ((uint64_t)k3 << 32) | (unsigned)(255 - base - 3);
    } else {
        // exact fallback (unreachable in practice): 8 rounds of wave argmax
        unsigned mk0 = keep ? k0 : 0x80000000u;
        unsigned mk1 = keep ? k1 : 0x80000000u;
        unsigned mk2 = keep ? k2 : 0x80000000u;
        unsigned mk3 = keep ? k3 : 0x80000000u;
        for (int r = 0; r < TK; ++r) {
            unsigned h = umax_(umax_(mk0, mk1), umax_(mk2, mk3));
            unsigned m = h;
            m = umax_(m, (unsigned)__shfl_xor((int)m, 1));
            m = umax_(m, (unsigned)__shfl_xor((int)m, 2));
            m = umax_(m, (unsigned)__shfl_xor((int)m, 4));
            m = umax_(m, (unsigned)__shfl_xor((int)m, 8));
            const unsigned M = umax_(umax_(rlaneu(m, 0), rlaneu(m, 16)),
                                     umax_(rlaneu(m, 32), rlaneu(m, 48)));
            const unsigned long long bl = __ballot(h == M);
            const int wl = __ffsll(bl) - 1;
            const unsigned long long sb0 = __ballot(mk0 == M);
            const unsigned long long sb1 = __ballot(mk1 == M);
            const unsigned long long sb2 = __ballot(mk2 == M);
            const int slot = ((sb0 >> wl) & 1) ? 0 : ((sb1 >> wl) & 1) ? 1
                           : ((sb2 >> wl) & 1) ? 2 : 3;
            if (lane == r)
                *reinterpret_cast<uint64_t*>(&row[2 * r]) =
                    ((uint64_t)M << 32) | (unsigned)(255 - (wl * 4 + slot));
            const bool iw = (lane == wl);
            mk0 = (iw && slot == 0) ? 0u : mk0;
            mk1 = (iw && slot == 1) ? 0u : mk1;
            mk2 = (iw && slot == 2) ? 0u : mk2;
            mk3 = (iw && slot == 3) ? 0u : mk3;
        }
        cnt = 8;
    }
    // pad slots cnt..cnt+3 with zero keys (INS8 no-ops) for batched phase-2
    if (lane < 4)
        *reinterpret_cast<uint64_t*>(&row[2 * (cnt + lane)]) = 0ull;
    if (lane == 0) row[CNT_OFF] = cnt;
}

__global__ __launch_bounds__(256, 5) void route_kernel(
    const float* __restrict__ logits,
    const float* __restrict__ bias,
    float* __restrict__ out_idx_f,   // [T,8] indices stored as float
    float* __restrict__ out_w,       // [T,8] weights
    int T)
{
    __shared__ uint32_t cand[TPB * CDW];   // 19456 B (16B-aligned rows)
    __shared__ float    bias_s[NE];        // 1024 B

    const int lane = threadIdx.x & 63;
    const int wvi  = threadIdx.x >> 6;
    const long long tok0 = (long long)blockIdx.x * TPB;

    bias_s[threadIdx.x] = bias[threadIdx.x];   // 256 threads == NE

    // ========== phase 1: wave-per-token scoring, 2-token ILP pairs ==========
    {
        const float4 bias4 = *reinterpret_cast<const float4*>(bias + lane * 4);
        const pf2 biasL = {bias4.x, bias4.y};
        const pf2 biasH = {bias4.z, bias4.w};
        const float* lp = logits + (tok0 + wvi * 16) * NE + lane * 4;
        uint32_t* wrow = &cand[(wvi * 16) * CDW];
        const int bpa = (lane & 7) << 5;   // bpermute byte-addr: lane (lane&7)*8

        float4 cA = *reinterpret_cast<const float4*>(lp);
        float4 cB = *reinterpret_cast<const float4*>(lp + NE);
        float4 nA, nB;
        for (int i = 0; i < 8; ++i) {
            if (i < 7) {
                nA = *reinterpret_cast<const float4*>(lp + (2 * i + 2) * NE);
                nB = *reinterpret_cast<const float4*>(lp + (2 * i + 3) * NE);
            }
            score_token(cA, biasL, biasH, lane, bpa, wrow + (2 * i) * CDW);
            score_token(cB, biasL, biasH, lane, bpa, wrow + (2 * i + 1) * CDW);
            cA = nA; cB = nB;
        }
    }
    __syncthreads();

    // ========== phase 2: thread-per-token batched top-8 + output ==========
    if (threadIdx.x < TPB) {
        uint32_t* row = &cand[threadIdx.x * CDW];
        const long long t = tok0 + threadIdx.x;
        const unsigned cnt = row[CNT_OFF];
        const unsigned iters = (cnt + 3) >> 2;

        uint64_t v0 = 0, v1 = 0, v2 = 0, v3 = 0, v4 = 0, v5 = 0, v6 = 0, v7 = 0;
        const ulonglong2* rp = reinterpret_cast<const ulonglong2*>(row);
        for (unsigned it = 0; it < iters; ++it) {
            const ulonglong2 a = rp[2 * it];       // ds_read_b128
            const ulonglong2 b = rp[2 * it + 1];   // ds_read_b128
            INS8(a.x); INS8(a.y); INS8(b.x); INS8(b.y);
        }

        const int e0 = 255 - (int)(v0 & 255u);
        const int e1 = 255 - (int)(v1 & 255u);
        const int e2 = 255 - (int)(v2 & 255u);
        const int e3 = 255 - (int)(v3 & 255u);
        const int e4 = 255 - (int)(v4 & 255u);
        const int e5 = 255 - (int)(v5 & 255u);
        const int e6 = 255 - (int)(v6 & 255u);
        const int e7 = 255 - (int)(v7 & 255u);
        const float s0 = inv_ordkey((unsigned)(v0 >> 32)) - bias_s[e0];
        const float s1 = inv_ordkey((unsigned)(v1 >> 32)) - bias_s[e1];
        const float s2 = inv_ordkey((unsigned)(v2 >> 32)) - bias_s[e2];
        const float s3 = inv_ordkey((unsigned)(v3 >> 32)) - bias_s[e3];
        const float s4 = inv_ordkey((unsigned)(v4 >> 32)) - bias_s[e4];
        const float s5 = inv_ordkey((unsigned)(v5 >> 32)) - bias_s[e5];
        const float s6 = inv_ordkey((unsigned)(v6 >> 32)) - bias_s[e6];
        const float s7 = inv_ordkey((unsigned)(v7 >> 32)) - bias_s[e7];

        const float denom = ((s0 + s1) + (s2 + s3)) + ((s4 + s5) + (s6 + s7));
        const float scale = 2.5f * __builtin_amdgcn_rcpf(denom + 1e-20f);

        float4* oi = reinterpret_cast<float4*>(out_idx_f + t * TK);
        float4* ow = reinterpret_cast<float4*>(out_w + t * TK);
        oi[0] = make_float4((float)e0, (float)e1, (float)e2, (float)e3);
        oi[1] = make_float4((float)e4, (float)e5, (float)e6, (float)e7);
        ow[0] = make_float4(s0 * scale, s1 * scale, s2 * scale, s3 * scale);
        ow[1] = make_float4(s4 * scale, s5 * scale, s6 * scale, s7 * scale);
    }
}

extern "C" void kernel_launch(void* const* d_in, const int* in_sizes, int n_in,
                              void* d_out, int out_size, void* d_ws, size_t ws_size,
                              hipStream_t stream) {
    const float* logits = (const float*)d_in[0];
    const float* bias   = (const float*)d_in[1];
    const int T = in_sizes[0] / NE;

    float* out_idx_f = (float*)d_out;
    float* out_w     = (float*)d_out + (size_t)T * TK;

    const int grid = T / TPB;   // 262144 / 64 = 4096
    route_kernel<<<grid, 256, 0, stream>>>(logits, bias, out_idx_f, out_w, T);
}

// Round 16
// 88.790 us; speedup vs baseline: 1.0547x; 1.0195x over previous
//
#include <hip/hip_runtime.h>
#include <stdint.h>

#define NE 256      // experts
#define TKG 4       // top-k groups
#define TK 8        // top-k experts
#define TPB 64      // tokens per block (256 threads = 4 waves; 16 tokens/wave)
#define CDW 76      // dwords per token row: 36 u64 slots (32 cand + 4 pad) + cnt; 304B, 16B-aligned
#define CNT_OFF 72

typedef float pf2 __attribute__((ext_vector_type(2)));

// ---------- packed f32 VOP3P helpers (bit-identical IEEE, half the issues) ----------
__device__ __forceinline__ pf2 pk_fma_ss(pf2 a, pf2 b, pf2 cs) {
    pf2 d; asm("v_pk_fma_f32 %0, %1, %2, %3" : "=v"(d) : "v"(a), "v"(b), "s"(cs)); return d;
}
__device__ __forceinline__ pf2 pk_fma_sv(pf2 as, pf2 b, pf2 c) {
    pf2 d; asm("v_pk_fma_f32 %0, %1, %2, %3" : "=v"(d) : "s"(as), "v"(b), "v"(c)); return d;
}
__device__ __forceinline__ pf2 pk_fma_vv(pf2 a, pf2 b, pf2 c) {
    pf2 d; asm("v_pk_fma_f32 %0, %1, %2, %3" : "=v"(d) : "v"(a), "v"(b), "v"(c)); return d;
}
__device__ __forceinline__ pf2 pk_mul_s(pf2 a, pf2 bs) {
    pf2 d; asm("v_pk_mul_f32 %0, %1, %2" : "=v"(d) : "v"(a), "s"(bs)); return d;
}
__device__ __forceinline__ pf2 pk_mul_v(pf2 a, pf2 b) {
    pf2 d; asm("v_pk_mul_f32 %0, %1, %2" : "=v"(d) : "v"(a), "v"(b)); return d;
}
__device__ __forceinline__ pf2 pk_add_s(pf2 a, pf2 bs) {
    pf2 d; asm("v_pk_add_f32 %0, %1, %2" : "=v"(d) : "v"(a), "s"(bs)); return d;
}

// Bit-exact packed replica of numpy's SIMD float32 exp (Cephes FMA path).
// DO NOT TOUCH — validated bit-exact vs the np reference (rounds 3-15).
__device__ __forceinline__ pf2 np_expf2(pf2 v) {
    const pf2 LOG2E  = {1.44269504088896341f, 1.44269504088896341f};
    const pf2 NLN2HI = {-0.693359375f, -0.693359375f};
    const pf2 LN2LO  = {2.12194440e-4f, 2.12194440e-4f};
    const pf2 A0     = {1.9875691500E-4f, 1.9875691500E-4f};
    const pf2 A1     = {1.3981999507E-3f, 1.3981999507E-3f};
    const pf2 A2     = {8.3334519073E-3f, 8.3334519073E-3f};
    const pf2 A3     = {4.1665795894E-2f, 4.1665795894E-2f};
    const pf2 A4     = {1.6666665459E-1f, 1.6666665459E-1f};
    const pf2 A5     = {5.0000001201E-1f, 5.0000001201E-1f};
    const pf2 ONE    = {1.0f, 1.0f};

    pf2 m = pk_mul_s(v, LOG2E);
    pf2 q; q.x = rintf(m.x); q.y = rintf(m.y);
    pf2 t = pk_fma_sv(NLN2HI, q, v);
    t = pk_fma_sv(LN2LO, q, t);
    pf2 t2 = pk_mul_v(t, t);
    pf2 p = pk_fma_sv(A0, t, A1);
    p = pk_fma_ss(p, t, A2);
    p = pk_fma_ss(p, t, A3);
    p = pk_fma_ss(p, t, A4);
    p = pk_fma_ss(p, t, A5);
    p = pk_fma_vv(p, t2, t);
    p = pk_add_s(p, ONE);
    pf2 r;
    r.x = ldexpf(p.x, (int)q.x);
    r.y = ldexpf(p.y, (int)q.y);
    return r;
}

// Correctly-rounded 1/d for d in [1, 2^20] (validated r10-r15).
__device__ __forceinline__ float crdiv1(float d) {
    float y0 = __builtin_amdgcn_rcpf(d);
    float e0 = fmaf(-d, y0, 1.0f);
    float y1 = fmaf(e0, y0, y0);
    float e1 = fmaf(-d, y1, 1.0f);
    float y2 = fmaf(e1, y1, y1);
    float r  = fmaf(-d, y2, 1.0f);
    return fmaf(r, y2, y2);
}

// f32 -> monotone u32 (order-preserving). 0.0f -> 0x80000000.
__device__ __forceinline__ unsigned ordkey(float v) {
    int b = __float_as_int(v);
    return (unsigned)(b ^ ((b >> 31) | 0x80000000));
}
__device__ __forceinline__ float inv_ordkey(unsigned u) {
    unsigned b = (u & 0x80000000u) ? (u ^ 0x80000000u) : ~u;
    return __uint_as_float(b);
}

__device__ __forceinline__ float rlanef(float v, int l) {
    return __int_as_float(__builtin_amdgcn_readlane(__float_as_int(v), l));
}
__device__ __forceinline__ unsigned rlaneu(unsigned v, int l) {
    return (unsigned)__builtin_amdgcn_readlane((int)v, l);
}
__device__ __forceinline__ unsigned umax_(unsigned a, unsigned b) { return a > b ? a : b; }
__device__ __forceinline__ int mbcnt64(unsigned long long m) {
    return __builtin_amdgcn_mbcnt_hi((unsigned)(m >> 32),
           __builtin_amdgcn_mbcnt_lo((unsigned)m, 0u));
}

// DPP cross-lane read (pure VALU, no LDS).
template <int CTRL>
__device__ __forceinline__ float dppf(float x) {
    int xi = __float_as_int(x);
    return __int_as_float(__builtin_amdgcn_update_dpp(xi, xi, CTRL, 0xF, 0xF, false));
}
#define DPP_XOR1  0xB1   // quad_perm [1,0,3,2]
#define DPP_XOR2  0x4E   // quad_perm [2,3,0,1]
#define DPP_HMIRR 0x141  // row_half_mirror: l <-> l^7 within each 8
#define DPP_ROR8  0x128  // row_ror:8
#define DPP_BC15  0x142  // row_bcast15
#define DPP_BC31  0x143  // row_bcast31

// Branchless sorted-descending top-8 insertion (u64 = key<<32 | invidx).
// Zero candidates are exact no-ops.
#define INS8(cand) do {                                                \
    const uint64_t c_ = (cand);                                        \
    const bool q0 = c_ > v0, q1 = c_ > v1, q2 = c_ > v2, q3 = c_ > v3; \
    const bool q4 = c_ > v4, q5 = c_ > v5, q6 = c_ > v6, q7 = c_ > v7; \
    v7 = q7 ? (q6 ? v6 : c_) : v7;                                     \
    v6 = q6 ? (q5 ? v5 : c_) : v6;                                     \
    v5 = q5 ? (q4 ? v4 : c_) : v5;                                     \
    v4 = q4 ? (q3 ? v3 : c_) : v4;                                     \
    v3 = q3 ? (q2 ? v2 : c_) : v3;                                     \
    v2 = q2 ? (q1 ? v1 : c_) : v2;                                     \
    v1 = q1 ? (q0 ? v0 : c_) : v1;                                     \
    v0 = q0 ? c_ : v0;                                                 \
} while (0)

// Full per-token phase-1 — byte-identical logic to r14/r15.
__device__ __forceinline__ void score_token(
    const float4 cur, const pf2 biasL, const pf2 biasH,
    const int lane, const int bpa, uint32_t* row)
{
    const pf2 ONE = {1.0f, 1.0f};
    pf2 eA = np_expf2((pf2){-cur.x, -cur.y});
    pf2 eB = np_expf2((pf2){-cur.z, -cur.w});
    pf2 dA = pk_add_s(eA, ONE);
    pf2 dB = pk_add_s(eB, ONE);
    const float s0 = crdiv1(dA.x);
    const float s1 = crdiv1(dA.y);
    const float s2 = crdiv1(dB.x);
    const float s3 = crdiv1(dB.y);
    const float c0 = s0 + biasL.x;
    const float c1 = s1 + biasL.y;
    const float c2 = s2 + biasH.x;
    const float c3 = s3 + biasH.y;

    // local sorted top-2 of my 4 values
    float a1 = fmaxf(c0, c1), a2 = fminf(c0, c1);
    float d1 = fmaxf(c2, c3), d2 = fminf(c2, c3);
    float m1 = fmaxf(a1, d1);
    float m2 = fmaxf(fminf(a1, d1), fmaxf(a2, d2));

    // DPP butterfly within the 8-lane group (top-2 values tree-invariant)
    {
        float p1 = dppf<DPP_XOR1>(m1), p2 = dppf<DPP_XOR1>(m2);
        float n1 = fmaxf(m1, p1);
        m2 = fmaxf(fminf(m1, p1), fmaxf(m2, p2)); m1 = n1;
    }
    {
        float p1 = dppf<DPP_XOR2>(m1), p2 = dppf<DPP_XOR2>(m2);
        float n1 = fmaxf(m1, p1);
        m2 = fmaxf(fminf(m1, p1), fmaxf(m2, p2)); m1 = n1;
    }
    {
        float p1 = dppf<DPP_HMIRR>(m1), p2 = dppf<DPP_HMIRR>(m2);
        float n1 = fmaxf(m1, p1);
        m2 = fmaxf(fminf(m1, p1), fmaxf(m2, p2)); m1 = n1;
    }
    const float gs = m1 + m2;   // group-uniform

    // transpose-rank (one bpermute + 2 ballots + SALU byte popcounts)
    const float gb = __int_as_float(
        __builtin_amdgcn_ds_bpermute(bpa, __float_as_int(gs)));
    const unsigned long long gtm = __ballot(gb > gs);
    const unsigned long long eqm = __ballot(gb == gs);
    const unsigned long long term = gtm | (eqm & 0x7F3F1F0F07030100ull);
    unsigned km8 = 0;
    #pragma unroll
    for (int a = 0; a < 8; ++a)
        km8 |= (unsigned)(__popcll((term >> (8 * a)) & 0xFFull) < 4 ? 1u : 0u) << a;
    const int g = lane >> 3;
    const bool keep = (km8 >> g) & 1u;

    // tau0 = min over kept groups of m2 (DPP min-reduce; result at lane 63)
    const float inf_ = __uint_as_float(0x7F800000u);
    float mm = keep ? m2 : inf_;
    mm = fminf(mm, dppf<DPP_ROR8>(mm));
    mm = fminf(mm, dppf<DPP_BC15>(mm));
    mm = fminf(mm, dppf<DPP_BC31>(mm));
    const float t0f = rlanef(mm, 63);

    // candidate filter + ballot compaction (exec-masked stores)
    const bool cd0 = keep && (c0 >= t0f);
    const bool cd1 = keep && (c1 >= t0f);
    const bool cd2 = keep && (c2 >= t0f);
    const bool cd3 = keep && (c3 >= t0f);
    const unsigned long long b0 = __ballot(cd0);
    const unsigned long long b1 = __ballot(cd1);
    const unsigned long long b2 = __ballot(cd2);
    const unsigned long long b3 = __ballot(cd3);
    const unsigned p1_ = __popcll(b0);
    const unsigned p2_ = p1_ + __popcll(b1);
    const unsigned p3_ = p2_ + __popcll(b2);
    unsigned cnt = p3_ + __popcll(b3);

    const unsigned k0 = ordkey(c0);
    const unsigned k1 = ordkey(c1);
    const unsigned k2 = ordkey(c2);
    const unsigned k3 = ordkey(c3);

    const int base = lane * 4;
    if (cnt <= 32u) {
        if (cd0) *reinterpret_cast<uint64_t*>(&row[2 * (0u  + mbcnt64(b0))]) =
            ((uint64_t)k0 << 32) | (unsigned)(255 - base);
        if (cd1) *reinterpret_cast<uint64_t*>(&row[2 * (p1_ + mbcnt64(b1))]) =
            ((uint64_t)k1 << 32) | (unsigned)(255 - base - 1);
        if (cd2) *reinterpret_cast<uint64_t*>(&row[2 * (p2_ + mbcnt64(b2))]) =
            ((uint64_t)k2 << 32) | (unsigned)(255 - base - 2);
        if (cd3) *reinterpret_cast<uint64_t*>(&row[2 * (p3_ + mbcnt64(b3))]) =
            ((uint64_t)k3 << 32) | (unsigned)(255 - base - 3);
    } else {
        // exact fallback (unreachable in practice): 8 rounds of wave argmax
        unsigned mk0 = keep ? k0 : 0x80000000u;
        unsigned mk1 = keep ? k1 : 0x80000000u;
        unsigned mk2 = keep ? k2 : 0x80000000u;
        unsigned mk3 = keep ? k3 : 0x80000000u;
        for (int r = 0; r < TK; ++r) {
            unsigned h = umax_(umax_(mk0, mk1), umax_(mk2, mk3));
            unsigned m = h;
            m = umax_(m, (unsigned)__shfl_xor((int)m, 1));
            m = umax_(m, (unsigned)__shfl_xor((int)m, 2));
            m = umax_(m, (unsigned)__shfl_xor((int)m, 4));
            m = umax_(m, (unsigned)__shfl_xor((int)m, 8));
            const unsigned M = umax_(umax_(rlaneu(m, 0), rlaneu(m, 16)),
                                     umax_(rlaneu(m, 32), rlaneu(m, 48)));
            const unsigned long long bl = __ballot(h == M);
            const int wl = __ffsll(bl) - 1;
            const unsigned long long sb0 = __ballot(mk0 == M);
            const unsigned long long sb1 = __ballot(mk1 == M);
            const unsigned long long sb2 = __ballot(mk2 == M);
            const int slot = ((sb0 >> wl) & 1) ? 0 : ((sb1 >> wl) & 1) ? 1
                           : ((sb2 >> wl) & 1) ? 2 : 3;
            if (lane == r)
                *reinterpret_cast<uint64_t*>(&row[2 * r]) =
                    ((uint64_t)M << 32) | (unsigned)(255 - (wl * 4 + slot));
            const bool iw = (lane == wl);
            mk0 = (iw && slot == 0) ? 0u : mk0;
            mk1 = (iw && slot == 1) ? 0u : mk1;
            mk2 = (iw && slot == 2) ? 0u : mk2;
            mk3 = (iw && slot == 3) ? 0u : mk3;
        }
        cnt = 8;
    }
    // pad slots cnt..cnt+3 with zero keys (INS8 no-ops) for batched phase-2
    if (lane < 4)
        *reinterpret_cast<uint64_t*>(&row[2 * (cnt + lane)]) = 0ull;
    if (lane == 0) row[CNT_OFF] = cnt;
}

__global__ __launch_bounds__(256, 4) void route_kernel(
    const float* __restrict__ logits,
    const float* __restrict__ bias,
    float* __restrict__ out_idx_f,   // [T,8] indices stored as float
    float* __restrict__ out_w,       // [T,8] weights
    int T)
{
    __shared__ uint32_t cand[TPB * CDW];   // 19456 B (16B-aligned rows)
    __shared__ float    bias_s[NE];        // 1024 B

    const int lane = threadIdx.x & 63;
    const int wvi  = threadIdx.x >> 6;
    const long long tok0 = (long long)blockIdx.x * TPB;

    bias_s[threadIdx.x] = bias[threadIdx.x];   // 256 threads == NE

    // ===== phase 1: wave-per-token scoring, 2-token ILP, 2-deep prefetch =====
    // Loads for pair i+2 issue at iteration i -> ~2 iterations (>=900 cyc) of
    // compute cover the HBM latency, vs 1 iteration (~450 cyc) before.
    {
        const float4 bias4 = *reinterpret_cast<const float4*>(bias + lane * 4);
        const pf2 biasL = {bias4.x, bias4.y};
        const pf2 biasH = {bias4.z, bias4.w};
        const float* lp = logits + (tok0 + wvi * 16) * NE + lane * 4;
        uint32_t* wrow = &cand[(wvi * 16) * CDW];
        const int bpa = (lane & 7) << 5;   // bpermute byte-addr: lane (lane&7)*8

        float4 cA = *reinterpret_cast<const float4*>(lp);            // pair 0
        float4 cB = *reinterpret_cast<const float4*>(lp + NE);
        float4 dA = *reinterpret_cast<const float4*>(lp + 2 * NE);   // pair 1
        float4 dB = *reinterpret_cast<const float4*>(lp + 3 * NE);
        float4 eA, eB;
        for (int i = 0; i < 8; ++i) {
            if (i < 6) {   // issue loads for pair i+2
                eA = *reinterpret_cast<const float4*>(lp + (2 * i + 4) * NE);
                eB = *reinterpret_cast<const float4*>(lp + (2 * i + 5) * NE);
            }
            score_token(cA, biasL, biasH, lane, bpa, wrow + (2 * i) * CDW);
            score_token(cB, biasL, biasH, lane, bpa, wrow + (2 * i + 1) * CDW);
            cA = dA; cB = dB; dA = eA; dB = eB;
        }
    }
    __syncthreads();

    // ========== phase 2: thread-per-token batched top-8 + output ==========
    if (threadIdx.x < TPB) {
        uint32_t* row = &cand[threadIdx.x * CDW];
        const long long t = tok0 + threadIdx.x;
        const unsigned cnt = row[CNT_OFF];
        const unsigned iters = (cnt + 3) >> 2;

        uint64_t v0 = 0, v1 = 0, v2 = 0, v3 = 0, v4 = 0, v5 = 0, v6 = 0, v7 = 0;
        const ulonglong2* rp = reinterpret_cast<const ulonglong2*>(row);
        for (unsigned it = 0; it < iters; ++it) {
            const ulonglong2 a = rp[2 * it];       // ds_read_b128
            const ulonglong2 b = rp[2 * it + 1];   // ds_read_b128
            INS8(a.x); INS8(a.y); INS8(b.x); INS8(b.y);
        }

        const int e0 = 255 - (int)(v0 & 255u);
        const int e1 = 255 - (int)(v1 & 255u);
        const int e2 = 255 - (int)(v2 & 255u);
        const int e3 = 255 - (int)(v3 & 255u);
        const int e4 = 255 - (int)(v4 & 255u);
        const int e5 = 255 - (int)(v5 & 255u);
        const int e6 = 255 - (int)(v6 & 255u);
        const int e7 = 255 - (int)(v7 & 255u);
        const float s0 = inv_ordkey((unsigned)(v0 >> 32)) - bias_s[e0];
        const float s1 = inv_ordkey((unsigned)(v1 >> 32)) - bias_s[e1];
        const float s2 = inv_ordkey((unsigned)(v2 >> 32)) - bias_s[e2];
        const float s3 = inv_ordkey((unsigned)(v3 >> 32)) - bias_s[e3];
        const float s4 = inv_ordkey((unsigned)(v4 >> 32)) - bias_s[e4];
        const float s5 = inv_ordkey((unsigned)(v5 >> 32)) - bias_s[e5];
        const float s6 = inv_ordkey((unsigned)(v6 >> 32)) - bias_s[e6];
        const float s7 = inv_ordkey((unsigned)(v7 >> 32)) - bias_s[e7];

        const float denom = ((s0 + s1) + (s2 + s3)) + ((s4 + s5) + (s6 + s7));
        const float scale = 2.5f * __builtin_amdgcn_rcpf(denom + 1e-20f);

        float4* oi = reinterpret_cast<float4*>(out_idx_f + t * TK);
        float4* ow = reinterpret_cast<float4*>(out_w + t * TK);
        oi[0] = make_float4((float)e0, (float)e1, (float)e2, (float)e3);
        oi[1] = make_float4((float)e4, (float)e5, (float)e6, (float)e7);
        ow[0] = make_float4(s0 * scale, s1 * scale, s2 * scale, s3 * scale);
        ow[1] = make_float4(s4 * scale, s5 * scale, s6 * scale, s7 * scale);
    }
}

extern "C" void kernel_launch(void* const* d_in, const int* in_sizes, int n_in,
                              void* d_out, int out_size, void* d_ws, size_t ws_size,
                              hipStream_t stream) {
    const float* logits = (const float*)d_in[0];
    const float* bias   = (const float*)d_in[1];
    const int T = in_sizes[0] / NE;

    float* out_idx_f = (float*)d_out;
    float* out_w     = (float*)d_out + (size_t)T * TK;

    const int grid = T / TPB;   // 262144 / 64 = 4096
    route_kernel<<<grid, 256, 0, stream>>>(logits, bias, out_idx_f, out_w, T);
}